// Round 1
// baseline (589.704 us; speedup 1.0000x reference)
//
#include <hip/hip_runtime.h>

// ---------------------------------------------------------------------------
// Qwen3VL text-attention block. IO fp32; internal bf16 MFMA + fp32 accum.
//   K0: fp32 -> bf16 streaming convert of x, [wq;wk;wv], wo
//   K1: fused QKV projection GEMM (256^2 8-phase pipeline; V written TRANSPOSED)
//   K2: per-head RMSNorm + RoPE (softmax scale folded into q)
//   K3: causal flash attention, MFMA QK^T + PV, fixed-max softmax
//   K4: output projection GEMM (same 256^2 8-phase template)
// GEMM K1/K4: 256x256 tile, BK=64, 512 thr (8 waves, 2Mx4N), double-buffered
// 128 KiB LDS, one half-tile (128x64) staged per phase via global_load_lds,
// counted s_waitcnt vmcnt(4) at K-tile boundaries (never 0 in the loop),
// raw s_barrier (no __syncthreads vmcnt-drain), setprio(1) around MFMA.
// All MFMA LDS tiles use the XOR granule swizzle:
//   slot(row, kg) = row*G + (kg ^ (row & (G-1)))   (granule = 8 bf16 = 16 B)
// ---------------------------------------------------------------------------

#define S_LEN 2048
#define DIM 4096
#define NH 32
#define NKV 8
#define HD 128
#define SCALE 0.08838834764831845f  // 1/sqrt(128)
#define NKT 64                      // K/64, K = 4096 for both GEMMs

typedef __attribute__((ext_vector_type(8))) short short8;
typedef __attribute__((ext_vector_type(4))) float f32x4;

__device__ __forceinline__ float bf2f(unsigned short u) {
  union { unsigned i; float f; } c; c.i = ((unsigned)u) << 16; return c.f;
}
__device__ __forceinline__ unsigned short f2bf(float f) {
  union { float f; unsigned u; } c; c.f = f;
  return (unsigned short)((c.u + 0x7fffu + ((c.u >> 16) & 1u)) >> 16);  // RNE
}
__device__ __forceinline__ void cvt8(const float* __restrict__ g,
                                     unsigned short* __restrict__ d) {
  const float4 a = *(const float4*)g;
  const float4 b = *(const float4*)(g + 4);
  short8 p;
  p[0] = (short)f2bf(a.x); p[1] = (short)f2bf(a.y);
  p[2] = (short)f2bf(a.z); p[3] = (short)f2bf(a.w);
  p[4] = (short)f2bf(b.x); p[5] = (short)f2bf(b.y);
  p[6] = (short)f2bf(b.z); p[7] = (short)f2bf(b.w);
  *(short8*)d = p;
}
__device__ __forceinline__ void storeC(float* p, float v) { *p = v; }
__device__ __forceinline__ void storeC(unsigned short* p, float v) { *p = f2bf(v); }

// ---------------------------------------------------------------------------
// K0: fp32 -> bf16 convert. One thread per 8-elem granule.
// ---------------------------------------------------------------------------
#define G_X   1048576u
#define G_WQ  2097152u
#define G_WK   524288u
#define G_WV   524288u
#define G_QKV (G_WQ + G_WK + G_WV)

__global__ __launch_bounds__(256)
void cvt_all(const float* __restrict__ x,  const float* __restrict__ wq,
             const float* __restrict__ wk, const float* __restrict__ wv,
             const float* __restrict__ wo,
             unsigned short* __restrict__ xb,
             unsigned short* __restrict__ wqkvb,
             unsigned short* __restrict__ wob) {
  const size_t g = (size_t)blockIdx.x * 256 + threadIdx.x;
  if (g < G_X) {
    cvt8(x + g * 8, xb + g * 8);
  } else if (g < G_X + G_QKV) {
    const size_t o = g - G_X;
    const float* s = (o < G_WQ) ? wq + o * 8
                   : (o < G_WQ + G_WK) ? wk + (o - G_WQ) * 8
                                       : wv + (o - G_WQ - G_WK) * 8;
    cvt8(s, wqkvb + o * 8);
  } else {
    const size_t o = g - (G_X + G_QKV);
    cvt8(wo + o * 8, wob + o * 8);
  }
}

// ---------------------------------------------------------------------------
// K1/K4: bf16 GEMM, C = A(Mx4096) @ B^T. 256x256 tile, 8-phase pipeline.
// Wave (wr=w>>2, wc=w&3) owns rows {mq*128+wr*64+mi*16} x cols
// {nq*128+wc*32+ni*16}: quadrant (mq,nq) touches exactly A-half mq, B-half nq.
// Phase order (0,0),(0,1),(1,1),(1,0); each phase stages the half-tile that
// just went dead: ph1=(kt+1).A1->!p, ph2=(kt+1).B0->!p, ph3=(kt+2).A0->p,
// ph4=(kt+2).B1->p. Boundary wait vmcnt(4) leaves ph3/ph4 loads in flight.
// ---------------------------------------------------------------------------

#define STAGE(XB, G0, HH, KT, LOFF)                                           \
  {                                                                            \
    _Pragma("unroll")                                                          \
    for (int j = 0; j < 2; ++j) {                                              \
      const int chunk = (w << 1) + j;                                          \
      const unsigned short* ga = (XB) +                                        \
          (size_t)((G0) + (HH) * 128 + chunk * 8 + r8) * 4096 +                \
          ((KT) << 6) + gsw;                                                   \
      __builtin_amdgcn_global_load_lds(                                        \
          (const __attribute__((address_space(1))) void*)ga,                   \
          (__attribute__((address_space(3))) void*)(ls + (LOFF) +              \
                                                    (HH) * 8192 + chunk * 512),\
          16, 0, 0);                                                           \
    }                                                                          \
  }

#define LDA(mq)                                                                \
  _Pragma("unroll") for (int mi = 0; mi < 4; ++mi)                             \
  _Pragma("unroll") for (int kc = 0; kc < 2; ++kc)                             \
    af[mi][kc] = *(const short8*)(ls + aoff +                                  \
        ((mq) * 128 + wr * 64 + mi * 16 + l15) * 64 +                          \
        (((kc << 2) + qd) ^ l7) * 8);

#define LDB(nq)                                                                \
  _Pragma("unroll") for (int ni = 0; ni < 2; ++ni)                             \
  _Pragma("unroll") for (int kc = 0; kc < 2; ++kc)                             \
    bfr[nq][ni][kc] = *(const short8*)(ls + boff +                             \
        ((nq) * 128 + wc * 32 + ni * 16 + l15) * 64 +                          \
        (((kc << 2) + qd) ^ l7) * 8);

#define MM(mq, nq)                                                             \
  __builtin_amdgcn_s_setprio(1);                                               \
  _Pragma("unroll") for (int mi = 0; mi < 4; ++mi)                             \
  _Pragma("unroll") for (int ni = 0; ni < 2; ++ni)                             \
  _Pragma("unroll") for (int kc = 0; kc < 2; ++kc)                             \
    acc[(mq) * 4 + mi][(nq) * 2 + ni] =                                        \
        __builtin_amdgcn_mfma_f32_16x16x32_bf16(                               \
            af[mi][kc], bfr[nq][ni][kc], acc[(mq) * 4 + mi][(nq) * 2 + ni],    \
            0, 0, 0);                                                          \
  __builtin_amdgcn_s_setprio(0);

template <int QKV, typename TC>
__global__ __launch_bounds__(512)
void gemm256(const unsigned short* __restrict__ A,
             const unsigned short* __restrict__ B,
             TC* __restrict__ C0,
             unsigned short* __restrict__ Ck,
             unsigned short* __restrict__ Cv) {
  // [buf][A/B][256 rows][8 granules swizzled] = 128 KiB
  __shared__ unsigned short ls[65536];

  const int t    = threadIdx.x;
  const int lane = t & 63;
  const int w    = t >> 6;                 // 0..7
  const int wr   = w >> 2;                 // 0..1
  const int wc   = w & 3;                  // 0..3
  const int m0   = blockIdx.y * 256;
  const int n0   = blockIdx.x * 256;
  const int l15  = lane & 15;
  const int qd   = lane >> 4;
  const int l7   = l15 & 7;
  const int r8   = lane >> 3;              // staging row within 8-chunk
  const int gsw  = ((lane & 7) ^ r8) * 8;  // swizzled staging granule (shorts)

  f32x4 acc[8][4];
#pragma unroll
  for (int a = 0; a < 8; ++a)
#pragma unroll
    for (int b = 0; b < 4; ++b)
#pragma unroll
      for (int e = 0; e < 4; ++e) acc[a][b][e] = 0.f;

  short8 af[4][2];       // current A-half fragments
  short8 bfr[2][2][2];   // both B-half fragments (B0 persists ph1->ph4)

  // ---- prologue: kt0 {A0,B1,A1,B0} -> buf0, kt1 {A0,B1} -> buf1
  STAGE(A, m0, 0, 0, 0);
  STAGE(B, n0, 1, 0, 16384);
  STAGE(A, m0, 1, 0, 0);
  STAGE(B, n0, 0, 0, 16384);
  STAGE(A, m0, 0, 1, 32768);
  STAGE(B, n0, 1, 1, 49152);
  asm volatile("s_waitcnt vmcnt(4)" ::: "memory");
  __builtin_amdgcn_s_barrier();

#pragma unroll 2
  for (int kt = 0; kt < NKT; ++kt) {
    const int p    = kt & 1;
    const int base = p << 15;              // this K-tile's buffer
    const int ob   = base ^ 32768;         // other buffer (kt+1)
    const int aoff = base;
    const int boff = base + 16384;
    const int kn1  = (kt + 1 < NKT) ? kt + 1 : NKT - 1;
    const int kn2  = (kt + 2 < NKT) ? kt + 2 : NKT - 1;

    // ---- phase 1: quadrant (0,0) ; stage (kt+1).A1
    LDA(0);
    LDB(0);
    STAGE(A, m0, 1, kn1, ob);
    __builtin_amdgcn_s_barrier();
    MM(0, 0);
    __builtin_amdgcn_s_barrier();

    // ---- phase 2: quadrant (0,1) ; stage (kt+1).B0
    LDB(1);
    STAGE(B, n0, 0, kn1, ob + 16384);
    __builtin_amdgcn_s_barrier();
    MM(0, 1);
    __builtin_amdgcn_s_barrier();

    // ---- phase 3: quadrant (1,1) ; stage (kt+2).A0 (A0 of buf p now dead)
    LDA(1);
    STAGE(A, m0, 0, kn2, base);
    __builtin_amdgcn_s_barrier();
    MM(1, 1);
    __builtin_amdgcn_s_barrier();

    // ---- phase 4: quadrant (1,0) ; stage (kt+2).B1 (B1 of buf p now dead)
    STAGE(B, n0, 1, kn2, base + 16384);
    __builtin_amdgcn_s_barrier();
    MM(1, 0);
    // counted wait: only ph3/ph4 stages (kt+2 halves) may stay in flight
    asm volatile("s_waitcnt vmcnt(4)" ::: "memory");
    __builtin_amdgcn_s_barrier();
  }

  // ---- epilogue: C/D layout col=lane&15, row=quad*4+reg
#pragma unroll
  for (int fm = 0; fm < 8; ++fm)
#pragma unroll
    for (int i = 0; i < 4; ++i) {
      const int grow = m0 + (fm >> 2) * 128 + wr * 64 + (fm & 3) * 16 + qd * 4 + i;
#pragma unroll
      for (int fn = 0; fn < 4; ++fn) {
        const int gcol = n0 + (fn >> 1) * 128 + wc * 32 + (fn & 1) * 16 + l15;
        const float v  = acc[fm][fn][i];
        if (QKV) {
          if (n0 < 4096)
            storeC((unsigned short*)C0 + (size_t)grow * 4096 + gcol, v);
          else if (n0 < 5120)
            Ck[(size_t)grow * 1024 + (gcol - 4096)] = f2bf(v);
          else  // V transposed: vT[d][token]
            Cv[(size_t)(gcol - 5120) * S_LEN + grow] = f2bf(v);
        } else {
          storeC(C0 + (size_t)grow * 4096 + gcol, v);
        }
      }
    }
}

// ---------------------------------------------------------------------------
// K2: RMSNorm (per head, 128 elems) + RoPE, in place on bf16 q and k.
// ---------------------------------------------------------------------------
__global__ __launch_bounds__(128)
void norm_rope(unsigned short* __restrict__ qb, unsigned short* __restrict__ kb,
               const float* __restrict__ cosb, const float* __restrict__ sinb,
               const float* __restrict__ qw, const float* __restrict__ kw) {
  const int hIdx = blockIdx.x;
  const int s    = blockIdx.y;
  const int d    = threadIdx.x;

  unsigned short* p; const float* wt;
  if (hIdx < NH) { p = qb + (size_t)s * (NH * HD) + hIdx * HD + d; wt = qw; }
  else           { p = kb + (size_t)s * (NKV * HD) + (hIdx - NH) * HD + d; wt = kw; }

  const float v = bf2f(*p);
  float ss = v * v;
  for (int off = 32; off; off >>= 1) ss += __shfl_down(ss, off);
  __shared__ float red[2];
  __shared__ float xs[128];
  if ((d & 63) == 0) red[d >> 6] = ss;
  __syncthreads();
  const float tot = red[0] + red[1];
  const float r   = rsqrtf(tot * (1.f / 128.f) + 1e-6f);
  const float xn  = v * r * wt[d];
  xs[d] = xn;
  __syncthreads();
  const float rot = (d < 64) ? -xs[d + 64] : xs[d - 64];
  float o = xn * cosb[s * HD + d] + rot * sinb[s * HD + d];
  if (hIdx < NH) o *= SCALE;  // fold softmax scale into q
  *p = f2bf(o);
}

// ---------------------------------------------------------------------------
// K3: causal flash attention, MFMA. 4 waves/block, (head, 64 q-rows)/block.
// ks: [key][dgran^key&15] (G=16 swizzle); vt: [d][kgran^d&7] (G=8 swizzle).
// Fixed-max softmax (post-RMSNorm scores bounded), deferred l-reduction.
// LDS: 16K + 16K + 9K = 41.2 KB.
// ---------------------------------------------------------------------------
#define PSTR 72  // P row stride (shorts)

__global__ __launch_bounds__(256)
void attn_mfma(const unsigned short* __restrict__ qB,
               const unsigned short* __restrict__ kB,
               const unsigned short* __restrict__ vT,
               unsigned short* __restrict__ oB) {
  __shared__ unsigned short ks[64 * 128];   // [key][16 granules, swizzled]
  __shared__ unsigned short vt[128 * 64];   // [d][8 granules, swizzled]
  __shared__ unsigned short Ps[4 * 16 * PSTR];

  const int t    = threadIdx.x;
  const int lane = t & 63;
  const int w    = t >> 6;
  const int qt   = (gridDim.x - 1) - blockIdx.x;  // heavy tiles first
  const int h    = blockIdx.y;
  const int kvh  = h >> 2;
  const int l15  = lane & 15;
  const int qd   = lane >> 4;
  const int l7   = l15 & 7;

  // staging index helpers
  const int kr16 = lane >> 4;                 // K staging: row within 4-chunk
  const int vr8  = lane >> 3;                 // V staging: row within 8-chunk
  const int vkg  = (lane & 7) ^ (vr8 & 7);    // V staging swizzled granule

  // preload Q A-fragments (q pre-scaled by 1/sqrt(d) in norm_rope)
  short8 qf[4];
  {
    const unsigned short* qp =
        qB + (size_t)(qt * 64 + w * 16 + l15) * (NH * HD) + h * HD + qd * 8;
#pragma unroll
    for (int s = 0; s < 4; ++s) qf[s] = *(const short8*)(qp + s * 32);
  }

  f32x4 O[8];
#pragma unroll
  for (int nt = 0; nt < 8; ++nt)
#pragma unroll
    for (int e = 0; e < 4; ++e) O[nt][e] = 0.f;
  float l_i[4] = {0.f, 0.f, 0.f, 0.f};

  unsigned short* Pw = Ps + w * (16 * PSTR);

  for (int kt = 0; kt <= qt; ++kt) {
    // ---- stage K-tile (64x128) and V^T-tile (128x64), swizzled, 16B DMA
#pragma unroll
    for (int c = 0; c < 4; ++c) {
      const int chunk = w * 4 + c;
      // K: key = chunk*4 + kr16; dgran = (lane&15) ^ (key&15)
      const int key = chunk * 4 + kr16;
      const int dg  = (lane & 15) ^ (key & 15);
      const unsigned short* gk = kB + (size_t)(kt * 64 + key) * (NKV * HD) +
                                 kvh * HD + dg * 8;
      __builtin_amdgcn_global_load_lds(
          (const __attribute__((address_space(1))) void*)gk,
          (__attribute__((address_space(3))) void*)(ks + chunk * 512), 16, 0, 0);
      // V: d = chunk*8 + vr8; kgran = vkg
      const int dv = chunk * 8 + vr8;
      const unsigned short* gv = vT + (size_t)(kvh * HD + dv) * S_LEN +
                                 kt * 64 + vkg * 8;
      __builtin_amdgcn_global_load_lds(
          (const __attribute__((address_space(1))) void*)gv,
          (__attribute__((address_space(3))) void*)(vt + chunk * 512), 16, 0, 0);
    }
    asm volatile("s_waitcnt vmcnt(0)" ::: "memory");
    __syncthreads();

    // ---- QK^T
    f32x4 S[4];
#pragma unroll
    for (int ct = 0; ct < 4; ++ct) {
#pragma unroll
      for (int e = 0; e < 4; ++e) S[ct][e] = 0.f;
#pragma unroll
      for (int s = 0; s < 4; ++s) {
        const int kg = (s * 4 + qd) ^ l15;  // G=16 swizzle (key&15 = l15)
        const short8 kf =
            *(const short8*)(ks + (ct * 16 + l15) * 128 + kg * 8);
        S[ct] = __builtin_amdgcn_mfma_f32_16x16x32_bf16(qf[s], kf, S[ct], 0, 0, 0);
      }
    }

    // ---- causal mask (diagonal tile only)
    if (kt == qt) {
#pragma unroll
      for (int ct = 0; ct < 4; ++ct)
#pragma unroll
        for (int i = 0; i < 4; ++i) {
          const int rloc = w * 16 + qd * 4 + i;
          const int cloc = ct * 16 + l15;
          if (cloc > rloc) S[ct][i] = -1e30f;
        }
    }

    // ---- P = exp(S), accumulate per-lane l, write P to per-wave LDS
#pragma unroll
    for (int ct = 0; ct < 4; ++ct)
#pragma unroll
      for (int i = 0; i < 4; ++i) {
        const float e = __expf(S[ct][i]);
        l_i[i] += e;
        Pw[(qd * 4 + i) * PSTR + ct * 16 + l15] = f2bf(e);
      }

    // ---- PV: O += P(16x64) * V(64x128)
    {
      const short8 pf0 = *(const short8*)(Pw + l15 * PSTR + qd * 8);
      const short8 pf1 = *(const short8*)(Pw + l15 * PSTR + 32 + qd * 8);
#pragma unroll
      for (int nt = 0; nt < 8; ++nt) {
        const int kg0 = qd ^ l7;        // half 0, G=8 swizzle (d&7 = l7)
        const int kg1 = (4 + qd) ^ l7;  // half 1
        const short8 vf0 =
            *(const short8*)(vt + (nt * 16 + l15) * 64 + kg0 * 8);
        O[nt] = __builtin_amdgcn_mfma_f32_16x16x32_bf16(pf0, vf0, O[nt], 0, 0, 0);
        const short8 vf1 =
            *(const short8*)(vt + (nt * 16 + l15) * 64 + kg1 * 8);
        O[nt] = __builtin_amdgcn_mfma_f32_16x16x32_bf16(pf1, vf1, O[nt], 0, 0, 0);
      }
    }
    __syncthreads();  // protect ks/vt before next tile's staging
  }

  // ---- deferred l reduction (16-lane butterfly), then scaled store
  float linv[4];
#pragma unroll
  for (int i = 0; i < 4; ++i) {
    float s = l_i[i];
#pragma unroll
    for (int off = 1; off < 16; off <<= 1) s += __shfl_xor(s, off);
    linv[i] = 1.f / s;
  }
#pragma unroll
  for (int nt = 0; nt < 8; ++nt)
#pragma unroll
    for (int i = 0; i < 4; ++i) {
      const size_t row = (size_t)(qt * 64 + w * 16 + qd * 4 + i);
      oB[row * (NH * HD) + h * HD + nt * 16 + l15] = f2bf(O[nt][i] * linv[i]);
    }
}

// ---------------------------------------------------------------------------
extern "C" void kernel_launch(void* const* d_in, const int* in_sizes, int n_in,
                              void* d_out, int out_size, void* d_ws, size_t ws_size,
                              hipStream_t stream) {
  const float* x    = (const float*)d_in[0];
  const float* cosb = (const float*)d_in[1];
  const float* sinb = (const float*)d_in[2];
  const float* wq   = (const float*)d_in[3];
  const float* wk   = (const float*)d_in[4];
  const float* wv   = (const float*)d_in[5];
  const float* wo   = (const float*)d_in[6];
  const float* qnw  = (const float*)d_in[7];
  const float* knw  = (const float*)d_in[8];

  unsigned short* q     = (unsigned short*)d_ws;            // 2048*4096
  unsigned short* k     = q + (size_t)S_LEN * DIM;          // 2048*1024
  unsigned short* vT    = k + (size_t)S_LEN * NKV * HD;     // 1024*2048
  unsigned short* att   = vT + (size_t)NKV * HD * S_LEN;    // 2048*4096
  unsigned short* xb    = att + (size_t)S_LEN * DIM;        // 2048*4096
  unsigned short* wqkvb = xb + (size_t)S_LEN * DIM;         // 6144*4096
  unsigned short* wob   = wqkvb + (size_t)6144 * DIM;       // 4096*4096

  // K0: convert fp32 inputs to bf16
  cvt_all<<<dim3(24576), dim3(256), 0, stream>>>(x, wq, wk, wv, wo, xb, wqkvb,
                                                 wob);
  // K1: QKV projection, N = 6144 -> 24 col tiles (V stored transposed)
  gemm256<1, unsigned short>
      <<<dim3(24, 8), dim3(512), 0, stream>>>(xb, wqkvb, q, k, vT);
  // K2: RMSNorm + RoPE
  norm_rope<<<dim3(NH + NKV, S_LEN), dim3(128), 0, stream>>>(q, k, cosb, sinb,
                                                             qnw, knw);
  // K3: causal MFMA attention
  attn_mfma<<<dim3(S_LEN / 64, NH), dim3(256), 0, stream>>>(q, k, vT, att);
  // K4: output projection, N = 4096 -> 16 col tiles
  gemm256<0, float>
      <<<dim3(16, 8), dim3(512), 0, stream>>>(att, wob, (float*)d_out,
                                              nullptr, nullptr);
}

// Round 2
// 533.001 us; speedup vs baseline: 1.1064x; 1.1064x over previous
//
#include <hip/hip_runtime.h>

// ---------------------------------------------------------------------------
// Qwen3VL text-attention block. IO fp32; internal bf16 MFMA + fp32 accum.
//   K0: fp32 -> bf16 streaming convert of x, [wq;wk;wv], wo
//   K1: fused QKV projection GEMM (bf16, global_load_lds; V written TRANSPOSED)
//   K2: per-head RMSNorm + RoPE, ONE WAVE PER HEAD (no LDS, no barriers)
//   K3: causal flash attention, 32 q-rows/wave (2 q-frags reuse each K/V read)
//   K4: output projection GEMM (bf16 A/B -> fp32 d_out)
// All MFMA LDS tiles use an XOR granule swizzle:
//   slot(row, kg) = row*G + (kg ^ (row & (G-1)))   (granule = 8 bf16 = 16 B)
// ---------------------------------------------------------------------------

#define S_LEN 2048
#define DIM 4096
#define NH 32
#define NKV 8
#define HD 128
#define SCALE 0.08838834764831845f  // 1/sqrt(128)

typedef __attribute__((ext_vector_type(8))) short short8;
typedef __attribute__((ext_vector_type(4))) float f32x4;

__device__ __forceinline__ float bf2f(unsigned short u) {
  union { unsigned i; float f; } c; c.i = ((unsigned)u) << 16; return c.f;
}
__device__ __forceinline__ unsigned short f2bf(float f) {
  union { float f; unsigned u; } c; c.f = f;
  return (unsigned short)((c.u + 0x7fffu + ((c.u >> 16) & 1u)) >> 16);  // RNE
}
__device__ __forceinline__ void cvt8(const float* __restrict__ g,
                                     unsigned short* __restrict__ d) {
  const float4 a = *(const float4*)g;
  const float4 b = *(const float4*)(g + 4);
  short8 p;
  p[0] = (short)f2bf(a.x); p[1] = (short)f2bf(a.y);
  p[2] = (short)f2bf(a.z); p[3] = (short)f2bf(a.w);
  p[4] = (short)f2bf(b.x); p[5] = (short)f2bf(b.y);
  p[6] = (short)f2bf(b.z); p[7] = (short)f2bf(b.w);
  *(short8*)d = p;
}
__device__ __forceinline__ void storeC(float* p, float v) { *p = v; }
__device__ __forceinline__ void storeC(unsigned short* p, float v) { *p = f2bf(v); }

// ---------------------------------------------------------------------------
// K0: fp32 -> bf16 convert. One thread per 8-elem granule.
// ---------------------------------------------------------------------------
#define G_X   1048576u
#define G_WQ  2097152u
#define G_WK   524288u
#define G_WV   524288u
#define G_QKV (G_WQ + G_WK + G_WV)

__global__ __launch_bounds__(256)
void cvt_all(const float* __restrict__ x,  const float* __restrict__ wq,
             const float* __restrict__ wk, const float* __restrict__ wv,
             const float* __restrict__ wo,
             unsigned short* __restrict__ xb,
             unsigned short* __restrict__ wqkvb,
             unsigned short* __restrict__ wob) {
  const size_t g = (size_t)blockIdx.x * 256 + threadIdx.x;
  if (g < G_X) {
    cvt8(x + g * 8, xb + g * 8);
  } else if (g < G_X + G_QKV) {
    const size_t o = g - G_X;
    const float* s = (o < G_WQ) ? wq + o * 8
                   : (o < G_WQ + G_WK) ? wk + (o - G_WQ) * 8
                                       : wv + (o - G_WQ - G_WK) * 8;
    cvt8(s, wqkvb + o * 8);
  } else {
    const size_t o = g - (G_X + G_QKV);
    cvt8(wo + o * 8, wob + o * 8);
  }
}

// ---------------------------------------------------------------------------
// K1/K4: bf16 GEMM, C = A(MxK) @ B^T. 128x128 tile, BK=64, global_load_lds
// staging, 4 waves x (4x4) 16x16x32 MFMA. LDS rows (64 k = 8 granules)
// XOR-swizzled with G=8.
// ---------------------------------------------------------------------------
template <int QKV, typename TC>
__global__ __launch_bounds__(256)
void gemm16(const unsigned short* __restrict__ A,
            const unsigned short* __restrict__ B,
            TC* __restrict__ C0,
            unsigned short* __restrict__ Ck,
            unsigned short* __restrict__ Cv, int K) {
  __shared__ unsigned short lsA[128 * 64];
  __shared__ unsigned short lsB[128 * 64];

  const int t    = threadIdx.x;
  const int lane = t & 63;
  const int w    = t >> 6;
  const int m0   = blockIdx.y * 128;
  const int n0   = blockIdx.x * 128;

  f32x4 acc[4][4];
#pragma unroll
  for (int a = 0; a < 4; ++a)
#pragma unroll
    for (int b = 0; b < 4; ++b)
#pragma unroll
      for (int e = 0; e < 4; ++e) acc[a][b][e] = 0.f;

  const int l15  = lane & 15;
  const int qd   = lane >> 4;
  const int wr   = w >> 1, wc = w & 1;
  const int sr8  = lane >> 3;                       // staging row in 8-chunk
  const int skg  = (lane & 7) ^ sr8;                // swizzled staging granule
  const int l7   = l15 & 7;

  const int nkb = K >> 6;
  for (int kb = 0; kb < nkb; ++kb) {
    const int k0 = kb << 6;
#pragma unroll
    for (int c = 0; c < 4; ++c) {
      const int chunk = c * 4 + w;         // wave-uniform
      const int row   = chunk * 8 + sr8;
      const unsigned short* ga = A + (size_t)(m0 + row) * K + k0 + skg * 8;
      const unsigned short* gb = B + (size_t)(n0 + row) * K + k0 + skg * 8;
      __builtin_amdgcn_global_load_lds(
          (const __attribute__((address_space(1))) void*)ga,
          (__attribute__((address_space(3))) void*)(lsA + chunk * 512), 16, 0, 0);
      __builtin_amdgcn_global_load_lds(
          (const __attribute__((address_space(1))) void*)gb,
          (__attribute__((address_space(3))) void*)(lsB + chunk * 512), 16, 0, 0);
    }
    asm volatile("s_waitcnt vmcnt(0)" ::: "memory");
    __syncthreads();

#pragma unroll
    for (int half = 0; half < 2; ++half) {
      const int kg = (half * 4 + qd) ^ l7;  // swizzled read granule
      short8 af[4], bf[4];
#pragma unroll
      for (int mi = 0; mi < 4; ++mi)
        af[mi] = *(const short8*)(lsA + (wr * 64 + mi * 16 + l15) * 64 + kg * 8);
#pragma unroll
      for (int ni = 0; ni < 4; ++ni)
        bf[ni] = *(const short8*)(lsB + (wc * 64 + ni * 16 + l15) * 64 + kg * 8);
#pragma unroll
      for (int mi = 0; mi < 4; ++mi)
#pragma unroll
        for (int ni = 0; ni < 4; ++ni)
          acc[mi][ni] = __builtin_amdgcn_mfma_f32_16x16x32_bf16(
              af[mi], bf[ni], acc[mi][ni], 0, 0, 0);
    }
    __syncthreads();
  }

  // epilogue: C/D layout col=lane&15, row=quad*4+reg
#pragma unroll
  for (int mi = 0; mi < 4; ++mi)
#pragma unroll
    for (int i = 0; i < 4; ++i) {
      const int grow = m0 + wr * 64 + mi * 16 + qd * 4 + i;
#pragma unroll
      for (int ni = 0; ni < 4; ++ni) {
        const int gcol = n0 + wc * 64 + ni * 16 + l15;
        if (QKV) {
          if (n0 < 4096)
            storeC((unsigned short*)C0 + (size_t)grow * 4096 + gcol,
                   acc[mi][ni][i]);
          else if (n0 < 5120)
            Ck[(size_t)grow * 1024 + (gcol - 4096)] = f2bf(acc[mi][ni][i]);
          else  // V transposed: vT[d][token]
            Cv[(size_t)(gcol - 5120) * S_LEN + grow] = f2bf(acc[mi][ni][i]);
        } else {
          storeC(C0 + (size_t)grow * 4096 + gcol, acc[mi][ni][i]);
        }
      }
    }
}

// ---------------------------------------------------------------------------
// K2: RMSNorm + RoPE, ONE WAVE PER HEAD. Lane l owns dims {l, l+64} -- the
// rotate-half pair is lane-local; RMS reduce is a 64-lane shuffle butterfly.
// No LDS, no barriers. Grid (S, 5) x 512 thr = 8 heads per block.
// ---------------------------------------------------------------------------
__global__ __launch_bounds__(512)
void norm_rope(unsigned short* __restrict__ qb, unsigned short* __restrict__ kb,
               const float* __restrict__ cosb, const float* __restrict__ sinb,
               const float* __restrict__ qw, const float* __restrict__ kw) {
  const int s    = blockIdx.x;
  const int w    = threadIdx.x >> 6;
  const int l    = threadIdx.x & 63;
  const int hh   = blockIdx.y * 8 + w;            // 0..39

  unsigned short* p; const float* wt;
  if (hh < NH) { p = qb + (size_t)s * (NH * HD) + hh * HD; wt = qw; }
  else         { p = kb + (size_t)s * (NKV * HD) + (hh - NH) * HD; wt = kw; }

  const float v0 = bf2f(p[l]);
  const float v1 = bf2f(p[l + 64]);
  float ss = v0 * v0 + v1 * v1;
#pragma unroll
  for (int off = 32; off; off >>= 1) ss += __shfl_xor(ss, off);
  const float r = rsqrtf(ss * (1.f / 128.f) + 1e-6f);

  const float xn0 = v0 * r * wt[l];
  const float xn1 = v1 * r * wt[l + 64];
  const float c0 = cosb[s * HD + l],      s0 = sinb[s * HD + l];
  const float c1 = cosb[s * HD + l + 64], s1 = sinb[s * HD + l + 64];
  float o0 = xn0 * c0 - xn1 * s0;
  float o1 = xn1 * c1 + xn0 * s1;
  if (hh < NH) { o0 *= SCALE; o1 *= SCALE; }  // fold softmax scale into q
  p[l]      = f2bf(o0);
  p[l + 64] = f2bf(o1);
}

// ---------------------------------------------------------------------------
// K3: causal flash attention, MFMA. 4 waves/block, 128 q-rows/block,
// 32 q-rows (2 q-frags) per wave: every kf/vf LDS read feeds 2 MFMAs ->
// halves the LDS-read bytes per FLOP (the measured bottleneck).
// ks: [key][dgran^key&15] (G=16 swizzle); vt: [d][kgran^d&7] (G=8 swizzle).
// Fixed-max softmax, deferred l-reduction.
// Causal balance: qt = (head&16) ? 15-bx : bx, so co-resident block pairs
// (id, id+256) have constant combined tile count.
// LDS: 16K + 16K + 18K = 50 KB -> 2 resident blocks/CU (8 waves).
// ---------------------------------------------------------------------------
#define PSTR 72  // P row stride (shorts)

__global__ __launch_bounds__(256)
void attn_mfma(const unsigned short* __restrict__ qB,
               const unsigned short* __restrict__ kB,
               const unsigned short* __restrict__ vT,
               unsigned short* __restrict__ oB) {
  __shared__ unsigned short ks[64 * 128];   // [key][16 granules, swizzled]
  __shared__ unsigned short vt[128 * 64];   // [d][8 granules, swizzled]
  __shared__ unsigned short Ps[4 * 32 * PSTR];

  const int t    = threadIdx.x;
  const int lane = t & 63;
  const int w    = t >> 6;
  const int h    = blockIdx.y;
  const int qt   = (h & 16) ? (15 - blockIdx.x) : blockIdx.x;  // pair-balanced
  const int q0   = qt * 128;
  const int kvh  = h >> 2;
  const int l15  = lane & 15;
  const int qd   = lane >> 4;
  const int l7   = l15 & 7;

  // staging index helpers
  const int kr16 = lane >> 4;                 // K staging: row within 4-chunk
  const int vr8  = lane >> 3;                 // V staging: row within 8-chunk
  const int vkg  = (lane & 7) ^ (vr8 & 7);    // V staging swizzled granule

  // preload Q A-fragments for 2 q-frags (q pre-scaled by 1/sqrt(d))
  short8 qf[2][4];
#pragma unroll
  for (int f = 0; f < 2; ++f) {
    const unsigned short* qp =
        qB + (size_t)(q0 + w * 32 + f * 16 + l15) * (NH * HD) + h * HD + qd * 8;
#pragma unroll
    for (int s = 0; s < 4; ++s) qf[f][s] = *(const short8*)(qp + s * 32);
  }

  f32x4 O[2][8];
#pragma unroll
  for (int f = 0; f < 2; ++f)
#pragma unroll
    for (int nt = 0; nt < 8; ++nt)
#pragma unroll
      for (int e = 0; e < 4; ++e) O[f][nt][e] = 0.f;
  float l_i[2][4] = {{0.f, 0.f, 0.f, 0.f}, {0.f, 0.f, 0.f, 0.f}};

  unsigned short* Pw = Ps + w * (32 * PSTR);

  const int nkt = 2 * qt + 2;  // tiles of 64 keys covering q0..q0+127
  for (int kt = 0; kt < nkt; ++kt) {
    // ---- stage K-tile (64x128) and V^T-tile (128x64), swizzled, 16B DMA
#pragma unroll
    for (int c = 0; c < 4; ++c) {
      const int chunk = w * 4 + c;
      const int key = chunk * 4 + kr16;
      const int dg  = (lane & 15) ^ (key & 15);
      const unsigned short* gk = kB + (size_t)(kt * 64 + key) * (NKV * HD) +
                                 kvh * HD + dg * 8;
      __builtin_amdgcn_global_load_lds(
          (const __attribute__((address_space(1))) void*)gk,
          (__attribute__((address_space(3))) void*)(ks + chunk * 512), 16, 0, 0);
      const int dv = chunk * 8 + vr8;
      const unsigned short* gv = vT + (size_t)(kvh * HD + dv) * S_LEN +
                                 kt * 64 + vkg * 8;
      __builtin_amdgcn_global_load_lds(
          (const __attribute__((address_space(1))) void*)gv,
          (__attribute__((address_space(3))) void*)(vt + chunk * 512), 16, 0, 0);
    }
    asm volatile("s_waitcnt vmcnt(0)" ::: "memory");
    __syncthreads();

    const int dk = kt - 2 * qt;               // >=0 on diagonal tiles
    const bool active = (dk <= 0) || (w >= 2);  // wave-uniform
    if (active) {
      // ---- QK^T: reuse each kf across both q-frags
      f32x4 S[2][4];
#pragma unroll
      for (int ct = 0; ct < 4; ++ct) {
#pragma unroll
        for (int e = 0; e < 4; ++e) { S[0][ct][e] = 0.f; S[1][ct][e] = 0.f; }
#pragma unroll
        for (int s = 0; s < 4; ++s) {
          const int kg = (s * 4 + qd) ^ l15;  // G=16 swizzle
          const short8 kf =
              *(const short8*)(ks + (ct * 16 + l15) * 128 + kg * 8);
          S[0][ct] = __builtin_amdgcn_mfma_f32_16x16x32_bf16(qf[0][s], kf,
                                                             S[0][ct], 0, 0, 0);
          S[1][ct] = __builtin_amdgcn_mfma_f32_16x16x32_bf16(qf[1][s], kf,
                                                             S[1][ct], 0, 0, 0);
        }
      }

      // ---- causal mask (diagonal tiles)
      if (dk >= 0) {
#pragma unroll
        for (int f = 0; f < 2; ++f)
#pragma unroll
          for (int ct = 0; ct < 4; ++ct)
#pragma unroll
            for (int i = 0; i < 4; ++i) {
              const int krel = dk * 64 + ct * 16 + l15;
              const int rrel = w * 32 + f * 16 + qd * 4 + i;
              if (krel > rrel) S[f][ct][i] = -1e30f;
            }
      }

      // ---- P = exp(S), accumulate per-lane l, write P to per-wave LDS
#pragma unroll
      for (int f = 0; f < 2; ++f)
#pragma unroll
        for (int ct = 0; ct < 4; ++ct)
#pragma unroll
          for (int i = 0; i < 4; ++i) {
            const float e = __expf(S[f][ct][i]);
            l_i[f][i] += e;
            Pw[(f * 16 + qd * 4 + i) * PSTR + ct * 16 + l15] = f2bf(e);
          }

      // ---- PV: O[f] += P[f](16x64) * V(64x128); vf reused across f
      {
        short8 pf[2][2];
#pragma unroll
        for (int f = 0; f < 2; ++f) {
          pf[f][0] = *(const short8*)(Pw + (f * 16 + l15) * PSTR + qd * 8);
          pf[f][1] = *(const short8*)(Pw + (f * 16 + l15) * PSTR + 32 + qd * 8);
        }
        const int kg0 = qd ^ l7;        // half 0, G=8 swizzle (d&7 = l7)
        const int kg1 = (4 + qd) ^ l7;  // half 1
#pragma unroll
        for (int nt = 0; nt < 8; ++nt) {
          const short8 vf0 =
              *(const short8*)(vt + (nt * 16 + l15) * 64 + kg0 * 8);
          const short8 vf1 =
              *(const short8*)(vt + (nt * 16 + l15) * 64 + kg1 * 8);
          O[0][nt] = __builtin_amdgcn_mfma_f32_16x16x32_bf16(pf[0][0], vf0,
                                                             O[0][nt], 0, 0, 0);
          O[1][nt] = __builtin_amdgcn_mfma_f32_16x16x32_bf16(pf[1][0], vf0,
                                                             O[1][nt], 0, 0, 0);
          O[0][nt] = __builtin_amdgcn_mfma_f32_16x16x32_bf16(pf[0][1], vf1,
                                                             O[0][nt], 0, 0, 0);
          O[1][nt] = __builtin_amdgcn_mfma_f32_16x16x32_bf16(pf[1][1], vf1,
                                                             O[1][nt], 0, 0, 0);
        }
      }
    }
    __syncthreads();  // protect ks/vt before next tile's staging
  }

  // ---- deferred l reduction (16-lane butterfly), then scaled store
  float linv[2][4];
#pragma unroll
  for (int f = 0; f < 2; ++f)
#pragma unroll
    for (int i = 0; i < 4; ++i) {
      float s = l_i[f][i];
#pragma unroll
      for (int off = 1; off < 16; off <<= 1) s += __shfl_xor(s, off);
      linv[f][i] = 1.f / s;
    }
#pragma unroll
  for (int f = 0; f < 2; ++f)
#pragma unroll
    for (int nt = 0; nt < 8; ++nt)
#pragma unroll
      for (int i = 0; i < 4; ++i) {
        const size_t row = (size_t)(q0 + w * 32 + f * 16 + qd * 4 + i);
        oB[row * (NH * HD) + h * HD + nt * 16 + l15] =
            f2bf(O[f][nt][i] * linv[f][i]);
      }
}

// ---------------------------------------------------------------------------
extern "C" void kernel_launch(void* const* d_in, const int* in_sizes, int n_in,
                              void* d_out, int out_size, void* d_ws, size_t ws_size,
                              hipStream_t stream) {
  const float* x    = (const float*)d_in[0];
  const float* cosb = (const float*)d_in[1];
  const float* sinb = (const float*)d_in[2];
  const float* wq   = (const float*)d_in[3];
  const float* wk   = (const float*)d_in[4];
  const float* wv   = (const float*)d_in[5];
  const float* wo   = (const float*)d_in[6];
  const float* qnw  = (const float*)d_in[7];
  const float* knw  = (const float*)d_in[8];

  unsigned short* q     = (unsigned short*)d_ws;            // 2048*4096
  unsigned short* k     = q + (size_t)S_LEN * DIM;          // 2048*1024
  unsigned short* vT    = k + (size_t)S_LEN * NKV * HD;     // 1024*2048
  unsigned short* att   = vT + (size_t)NKV * HD * S_LEN;    // 2048*4096
  unsigned short* xb    = att + (size_t)S_LEN * DIM;        // 2048*4096
  unsigned short* wqkvb = xb + (size_t)S_LEN * DIM;         // 6144*4096
  unsigned short* wob   = wqkvb + (size_t)6144 * DIM;       // 4096*4096

  // K0: convert fp32 inputs to bf16
  cvt_all<<<dim3(24576), dim3(256), 0, stream>>>(x, wq, wk, wv, wo, xb, wqkvb,
                                                 wob);
  // K1: QKV projection, N = 6144 -> 48 col tiles (V stored transposed)
  gemm16<1, unsigned short>
      <<<dim3(48, 16), dim3(256), 0, stream>>>(xb, wqkvb, q, k, vT, DIM);
  // K2: RMSNorm + RoPE, one wave per head
  norm_rope<<<dim3(S_LEN, 5), dim3(512), 0, stream>>>(q, k, cosb, sinb,
                                                      qnw, knw);
  // K3: causal MFMA attention, 128 q-rows/block
  attn_mfma<<<dim3(S_LEN / 128, NH), dim3(256), 0, stream>>>(q, k, vT, att);
  // K4: output projection, N = 4096 -> 32 col tiles
  gemm16<0, float>
      <<<dim3(32, 16), dim3(256), 0, stream>>>(att, wob, (float*)d_out,
                                               nullptr, nullptr, DIM);
}

// Round 3
// 529.470 us; speedup vs baseline: 1.1138x; 1.0067x over previous
//
#include <hip/hip_runtime.h>

// ---------------------------------------------------------------------------
// Qwen3VL text-attention block. IO fp32; internal bf16 MFMA + fp32 accum.
//   K0: fp32 -> bf16 streaming convert of x, [wq;wk;wv], wo
//   K1: fused QKV projection GEMM (bf16, global_load_lds; V written TRANSPOSED)
//   K2: per-head RMSNorm + RoPE, ONE WAVE PER HEAD (no LDS, no barriers)
//   K3: causal flash attention, 32 q-rows/wave, DOUBLE-BUFFERED K/V with
//       counted vmcnt(8) prefetch (never drains to 0 in the loop)
//   K4: output projection GEMM (bf16 A/B -> fp32 d_out)
// All MFMA LDS tiles use an XOR granule swizzle:
//   slot(row, kg) = row*G + (kg ^ (row & (G-1)))   (granule = 8 bf16 = 16 B)
// ---------------------------------------------------------------------------

#define S_LEN 2048
#define DIM 4096
#define NH 32
#define NKV 8
#define HD 128
#define SCALE 0.08838834764831845f  // 1/sqrt(128)

typedef __attribute__((ext_vector_type(8))) short short8;
typedef __attribute__((ext_vector_type(4))) float f32x4;

__device__ __forceinline__ float bf2f(unsigned short u) {
  union { unsigned i; float f; } c; c.i = ((unsigned)u) << 16; return c.f;
}
__device__ __forceinline__ unsigned short f2bf(float f) {
  union { float f; unsigned u; } c; c.f = f;
  return (unsigned short)((c.u + 0x7fffu + ((c.u >> 16) & 1u)) >> 16);  // RNE
}
__device__ __forceinline__ void cvt8(const float* __restrict__ g,
                                     unsigned short* __restrict__ d) {
  const float4 a = *(const float4*)g;
  const float4 b = *(const float4*)(g + 4);
  short8 p;
  p[0] = (short)f2bf(a.x); p[1] = (short)f2bf(a.y);
  p[2] = (short)f2bf(a.z); p[3] = (short)f2bf(a.w);
  p[4] = (short)f2bf(b.x); p[5] = (short)f2bf(b.y);
  p[6] = (short)f2bf(b.z); p[7] = (short)f2bf(b.w);
  *(short8*)d = p;
}
__device__ __forceinline__ void storeC(float* p, float v) { *p = v; }
__device__ __forceinline__ void storeC(unsigned short* p, float v) { *p = f2bf(v); }

// ---------------------------------------------------------------------------
// K0: fp32 -> bf16 convert. One thread per 8-elem granule.
// ---------------------------------------------------------------------------
#define G_X   1048576u
#define G_WQ  2097152u
#define G_WK   524288u
#define G_WV   524288u
#define G_QKV (G_WQ + G_WK + G_WV)

__global__ __launch_bounds__(256)
void cvt_all(const float* __restrict__ x,  const float* __restrict__ wq,
             const float* __restrict__ wk, const float* __restrict__ wv,
             const float* __restrict__ wo,
             unsigned short* __restrict__ xb,
             unsigned short* __restrict__ wqkvb,
             unsigned short* __restrict__ wob) {
  const size_t g = (size_t)blockIdx.x * 256 + threadIdx.x;
  if (g < G_X) {
    cvt8(x + g * 8, xb + g * 8);
  } else if (g < G_X + G_QKV) {
    const size_t o = g - G_X;
    const float* s = (o < G_WQ) ? wq + o * 8
                   : (o < G_WQ + G_WK) ? wk + (o - G_WQ) * 8
                                       : wv + (o - G_WQ - G_WK) * 8;
    cvt8(s, wqkvb + o * 8);
  } else {
    const size_t o = g - (G_X + G_QKV);
    cvt8(wo + o * 8, wob + o * 8);
  }
}

// ---------------------------------------------------------------------------
// K1/K4: bf16 GEMM, C = A(MxK) @ B^T. 128x128 tile, BK=64, global_load_lds
// staging, 4 waves x (4x4) 16x16x32 MFMA. LDS rows (64 k = 8 granules)
// XOR-swizzled with G=8.
// ---------------------------------------------------------------------------
template <int QKV, typename TC>
__global__ __launch_bounds__(256)
void gemm16(const unsigned short* __restrict__ A,
            const unsigned short* __restrict__ B,
            TC* __restrict__ C0,
            unsigned short* __restrict__ Ck,
            unsigned short* __restrict__ Cv, int K) {
  __shared__ unsigned short lsA[128 * 64];
  __shared__ unsigned short lsB[128 * 64];

  const int t    = threadIdx.x;
  const int lane = t & 63;
  const int w    = t >> 6;
  const int m0   = blockIdx.y * 128;
  const int n0   = blockIdx.x * 128;

  f32x4 acc[4][4];
#pragma unroll
  for (int a = 0; a < 4; ++a)
#pragma unroll
    for (int b = 0; b < 4; ++b)
#pragma unroll
      for (int e = 0; e < 4; ++e) acc[a][b][e] = 0.f;

  const int l15  = lane & 15;
  const int qd   = lane >> 4;
  const int wr   = w >> 1, wc = w & 1;
  const int sr8  = lane >> 3;                       // staging row in 8-chunk
  const int skg  = (lane & 7) ^ sr8;                // swizzled staging granule
  const int l7   = l15 & 7;

  const int nkb = K >> 6;
  for (int kb = 0; kb < nkb; ++kb) {
    const int k0 = kb << 6;
#pragma unroll
    for (int c = 0; c < 4; ++c) {
      const int chunk = c * 4 + w;         // wave-uniform
      const int row   = chunk * 8 + sr8;
      const unsigned short* ga = A + (size_t)(m0 + row) * K + k0 + skg * 8;
      const unsigned short* gb = B + (size_t)(n0 + row) * K + k0 + skg * 8;
      __builtin_amdgcn_global_load_lds(
          (const __attribute__((address_space(1))) void*)ga,
          (__attribute__((address_space(3))) void*)(lsA + chunk * 512), 16, 0, 0);
      __builtin_amdgcn_global_load_lds(
          (const __attribute__((address_space(1))) void*)gb,
          (__attribute__((address_space(3))) void*)(lsB + chunk * 512), 16, 0, 0);
    }
    asm volatile("s_waitcnt vmcnt(0)" ::: "memory");
    __syncthreads();

#pragma unroll
    for (int half = 0; half < 2; ++half) {
      const int kg = (half * 4 + qd) ^ l7;  // swizzled read granule
      short8 af[4], bf[4];
#pragma unroll
      for (int mi = 0; mi < 4; ++mi)
        af[mi] = *(const short8*)(lsA + (wr * 64 + mi * 16 + l15) * 64 + kg * 8);
#pragma unroll
      for (int ni = 0; ni < 4; ++ni)
        bf[ni] = *(const short8*)(lsB + (wc * 64 + ni * 16 + l15) * 64 + kg * 8);
#pragma unroll
      for (int mi = 0; mi < 4; ++mi)
#pragma unroll
        for (int ni = 0; ni < 4; ++ni)
          acc[mi][ni] = __builtin_amdgcn_mfma_f32_16x16x32_bf16(
              af[mi], bf[ni], acc[mi][ni], 0, 0, 0);
    }
    __syncthreads();
  }

  // epilogue: C/D layout col=lane&15, row=quad*4+reg
#pragma unroll
  for (int mi = 0; mi < 4; ++mi)
#pragma unroll
    for (int i = 0; i < 4; ++i) {
      const int grow = m0 + wr * 64 + mi * 16 + qd * 4 + i;
#pragma unroll
      for (int ni = 0; ni < 4; ++ni) {
        const int gcol = n0 + wc * 64 + ni * 16 + l15;
        if (QKV) {
          if (n0 < 4096)
            storeC((unsigned short*)C0 + (size_t)grow * 4096 + gcol,
                   acc[mi][ni][i]);
          else if (n0 < 5120)
            Ck[(size_t)grow * 1024 + (gcol - 4096)] = f2bf(acc[mi][ni][i]);
          else  // V transposed: vT[d][token]
            Cv[(size_t)(gcol - 5120) * S_LEN + grow] = f2bf(acc[mi][ni][i]);
        } else {
          storeC(C0 + (size_t)grow * 4096 + gcol, acc[mi][ni][i]);
        }
      }
    }
}

// ---------------------------------------------------------------------------
// K2: RMSNorm + RoPE, ONE WAVE PER HEAD. Lane l owns dims {l, l+64} -- the
// rotate-half pair is lane-local; RMS reduce is a 64-lane shuffle butterfly.
// No LDS, no barriers. Grid (S, 5) x 512 thr = 8 heads per block.
// ---------------------------------------------------------------------------
__global__ __launch_bounds__(512)
void norm_rope(unsigned short* __restrict__ qb, unsigned short* __restrict__ kb,
               const float* __restrict__ cosb, const float* __restrict__ sinb,
               const float* __restrict__ qw, const float* __restrict__ kw) {
  const int s    = blockIdx.x;
  const int w    = threadIdx.x >> 6;
  const int l    = threadIdx.x & 63;
  const int hh   = blockIdx.y * 8 + w;            // 0..39

  unsigned short* p; const float* wt;
  if (hh < NH) { p = qb + (size_t)s * (NH * HD) + hh * HD; wt = qw; }
  else         { p = kb + (size_t)s * (NKV * HD) + (hh - NH) * HD; wt = kw; }

  const float v0 = bf2f(p[l]);
  const float v1 = bf2f(p[l + 64]);
  float ss = v0 * v0 + v1 * v1;
#pragma unroll
  for (int off = 32; off; off >>= 1) ss += __shfl_xor(ss, off);
  const float r = rsqrtf(ss * (1.f / 128.f) + 1e-6f);

  const float xn0 = v0 * r * wt[l];
  const float xn1 = v1 * r * wt[l + 64];
  const float c0 = cosb[s * HD + l],      s0 = sinb[s * HD + l];
  const float c1 = cosb[s * HD + l + 64], s1 = sinb[s * HD + l + 64];
  float o0 = xn0 * c0 - xn1 * s0;
  float o1 = xn1 * c1 + xn0 * s1;
  if (hh < NH) { o0 *= SCALE; o1 *= SCALE; }  // fold softmax scale into q
  p[l]      = f2bf(o0);
  p[l + 64] = f2bf(o1);
}

// ---------------------------------------------------------------------------
// K3: causal flash attention, MFMA. 4 waves/block, 128 q-rows/block,
// 32 q-rows (2 q-frags) per wave. DOUBLE-BUFFERED K/V: tile kt+1's 8
// global_load_lds are issued before computing tile kt; boundary wait is
// s_waitcnt vmcnt(8) (only kt's loads), so HBM/L3 latency hides under
// compute. P-LDS is per-wave 16 rows, reused per q-frag (per-wave DS ops
// are in-order, so the f=1 overwrite after f=0's fragment reads is safe).
// ks: [key][dgran^key&15] (G=16 swizzle); vt: [d][kgran^d&7] (G=8 swizzle).
// Fixed-max softmax, deferred l-reduction.
// Causal balance: qt = (head&16) ? 15-bx : bx.
// LDS: 32K (ks x2) + 32K (vt x2) + 9K (Ps) = 73 KB -> 2 blocks/CU.
// ---------------------------------------------------------------------------
#define PSTR 72  // P row stride (shorts); 36 words -> perfect 32-bank spread

#define STAGE_KV(KT, BUF)                                                      \
  {                                                                            \
    unsigned short* ksb = ks + (BUF) * 8192;                                   \
    unsigned short* vtb = vt + (BUF) * 8192;                                   \
    _Pragma("unroll")                                                          \
    for (int c = 0; c < 4; ++c) {                                              \
      const int chunk = w * 4 + c;                                             \
      const int key = chunk * 4 + kr16;                                        \
      const int dg  = (lane & 15) ^ (key & 15);                                \
      const unsigned short* gk = kB + (size_t)((KT) * 64 + key) * (NKV * HD) + \
                                 kvh * HD + dg * 8;                            \
      __builtin_amdgcn_global_load_lds(                                        \
          (const __attribute__((address_space(1))) void*)gk,                   \
          (__attribute__((address_space(3))) void*)(ksb + chunk * 512),        \
          16, 0, 0);                                                           \
      const int dv = chunk * 8 + vr8;                                          \
      const unsigned short* gv = vT + (size_t)(kvh * HD + dv) * S_LEN +        \
                                 (KT) * 64 + vkg * 8;                          \
      __builtin_amdgcn_global_load_lds(                                        \
          (const __attribute__((address_space(1))) void*)gv,                   \
          (__attribute__((address_space(3))) void*)(vtb + chunk * 512),        \
          16, 0, 0);                                                           \
    }                                                                          \
  }

__global__ __launch_bounds__(256)
void attn_mfma(const unsigned short* __restrict__ qB,
               const unsigned short* __restrict__ kB,
               const unsigned short* __restrict__ vT,
               unsigned short* __restrict__ oB) {
  __shared__ unsigned short ks[2 * 64 * 128];  // dbuf [key][16 gran, swz]
  __shared__ unsigned short vt[2 * 64 * 128];  // dbuf [d][8 gran, swz]
  __shared__ unsigned short Ps[4 * 16 * PSTR]; // per-wave 16-row P buffer

  const int t    = threadIdx.x;
  const int lane = t & 63;
  const int w    = t >> 6;
  const int h    = blockIdx.y;
  const int qt   = (h & 16) ? (15 - blockIdx.x) : blockIdx.x;  // pair-balanced
  const int q0   = qt * 128;
  const int kvh  = h >> 2;
  const int l15  = lane & 15;
  const int qd   = lane >> 4;
  const int l7   = l15 & 7;

  // staging index helpers
  const int kr16 = lane >> 4;                 // K staging: row within 4-chunk
  const int vr8  = lane >> 3;                 // V staging: row within 8-chunk
  const int vkg  = (lane & 7) ^ (vr8 & 7);    // V staging swizzled granule

  // preload Q A-fragments for 2 q-frags (q pre-scaled by 1/sqrt(d))
  short8 qf[2][4];
#pragma unroll
  for (int f = 0; f < 2; ++f) {
    const unsigned short* qp =
        qB + (size_t)(q0 + w * 32 + f * 16 + l15) * (NH * HD) + h * HD + qd * 8;
#pragma unroll
    for (int s = 0; s < 4; ++s) qf[f][s] = *(const short8*)(qp + s * 32);
  }

  f32x4 O[2][8];
#pragma unroll
  for (int f = 0; f < 2; ++f)
#pragma unroll
    for (int nt = 0; nt < 8; ++nt)
#pragma unroll
      for (int e = 0; e < 4; ++e) O[f][nt][e] = 0.f;
  float l_i[2][4] = {{0.f, 0.f, 0.f, 0.f}, {0.f, 0.f, 0.f, 0.f}};

  unsigned short* Pw = Ps + w * (16 * PSTR);

  const int nkt = 2 * qt + 2;  // tiles of 64 keys covering q0..q0+127

  // prologue: stage tile 0 into buffer 0
  STAGE_KV(0, 0);

  for (int kt = 0; kt < nkt; ++kt) {
    const int cur = kt & 1;
    const int kn  = (kt + 1 < nkt) ? (kt + 1) : kt;  // clamp (dup harmless)
    // issue next tile's loads into the other buffer (stays in flight under
    // this tile's compute)
    STAGE_KV(kn, cur ^ 1);
    // wait only for THIS tile's 8 loads (issued one compute-phase ago)
    asm volatile("s_waitcnt vmcnt(8)" ::: "memory");
    __builtin_amdgcn_s_barrier();

    const unsigned short* ksb = ks + cur * 8192;
    const unsigned short* vtb = vt + cur * 8192;

    const int dk = kt - 2 * qt;                 // >=0 on diagonal tiles
    const bool active = (dk <= 0) || (w >= 2);  // wave-uniform
    if (active) {
      // ---- QK^T: reuse each kf across both q-frags
      f32x4 S[2][4];
      __builtin_amdgcn_s_setprio(1);
#pragma unroll
      for (int ct = 0; ct < 4; ++ct) {
#pragma unroll
        for (int e = 0; e < 4; ++e) { S[0][ct][e] = 0.f; S[1][ct][e] = 0.f; }
#pragma unroll
        for (int s = 0; s < 4; ++s) {
          const int kg = (s * 4 + qd) ^ l15;  // G=16 swizzle
          const short8 kf =
              *(const short8*)(ksb + (ct * 16 + l15) * 128 + kg * 8);
          S[0][ct] = __builtin_amdgcn_mfma_f32_16x16x32_bf16(qf[0][s], kf,
                                                             S[0][ct], 0, 0, 0);
          S[1][ct] = __builtin_amdgcn_mfma_f32_16x16x32_bf16(qf[1][s], kf,
                                                             S[1][ct], 0, 0, 0);
        }
      }
      __builtin_amdgcn_s_setprio(0);

      // ---- causal mask (diagonal tiles)
      if (dk >= 0) {
#pragma unroll
        for (int f = 0; f < 2; ++f)
#pragma unroll
          for (int ct = 0; ct < 4; ++ct)
#pragma unroll
            for (int i = 0; i < 4; ++i) {
              const int krel = dk * 64 + ct * 16 + l15;
              const int rrel = w * 32 + f * 16 + qd * 4 + i;
              if (krel > rrel) S[f][ct][i] = -1e30f;
            }
      }

      // ---- P = exp(S) per q-frag: write 16-row P, read A-frags back
      short8 pf[2][2];
#pragma unroll
      for (int f = 0; f < 2; ++f) {
#pragma unroll
        for (int ct = 0; ct < 4; ++ct)
#pragma unroll
          for (int i = 0; i < 4; ++i) {
            const float e = __expf(S[f][ct][i]);
            l_i[f][i] += e;
            Pw[(qd * 4 + i) * PSTR + ct * 16 + l15] = f2bf(e);
          }
        // per-wave DS ops are in-order: these reads complete before the
        // next f's writes to the same rows land
        pf[f][0] = *(const short8*)(Pw + l15 * PSTR + qd * 8);
        pf[f][1] = *(const short8*)(Pw + l15 * PSTR + 32 + qd * 8);
      }

      // ---- PV: O[f] += P[f](16x64) * V(64x128); vf reused across f
      {
        const int kg0 = qd ^ l7;        // half 0, G=8 swizzle (d&7 = l7)
        const int kg1 = (4 + qd) ^ l7;  // half 1
        __builtin_amdgcn_s_setprio(1);
#pragma unroll
        for (int nt = 0; nt < 8; ++nt) {
          const short8 vf0 =
              *(const short8*)(vtb + (nt * 16 + l15) * 64 + kg0 * 8);
          const short8 vf1 =
              *(const short8*)(vtb + (nt * 16 + l15) * 64 + kg1 * 8);
          O[0][nt] = __builtin_amdgcn_mfma_f32_16x16x32_bf16(pf[0][0], vf0,
                                                             O[0][nt], 0, 0, 0);
          O[1][nt] = __builtin_amdgcn_mfma_f32_16x16x32_bf16(pf[1][0], vf0,
                                                             O[1][nt], 0, 0, 0);
          O[0][nt] = __builtin_amdgcn_mfma_f32_16x16x32_bf16(pf[0][1], vf1,
                                                             O[0][nt], 0, 0, 0);
          O[1][nt] = __builtin_amdgcn_mfma_f32_16x16x32_bf16(pf[1][1], vf1,
                                                             O[1][nt], 0, 0, 0);
        }
        __builtin_amdgcn_s_setprio(0);
      }
    }
    // compute on `cur` done before next iter's prefetch overwrites it
    __builtin_amdgcn_s_barrier();
    __builtin_amdgcn_sched_barrier(0);
  }

  // ---- deferred l reduction (16-lane butterfly), then scaled store
  float linv[2][4];
#pragma unroll
  for (int f = 0; f < 2; ++f)
#pragma unroll
    for (int i = 0; i < 4; ++i) {
      float s = l_i[f][i];
#pragma unroll
      for (int off = 1; off < 16; off <<= 1) s += __shfl_xor(s, off);
      linv[f][i] = 1.f / s;
    }
#pragma unroll
  for (int f = 0; f < 2; ++f)
#pragma unroll
    for (int nt = 0; nt < 8; ++nt)
#pragma unroll
      for (int i = 0; i < 4; ++i) {
        const size_t row = (size_t)(q0 + w * 32 + f * 16 + qd * 4 + i);
        oB[row * (NH * HD) + h * HD + nt * 16 + l15] =
            f2bf(O[f][nt][i] * linv[f][i]);
      }
}

// ---------------------------------------------------------------------------
extern "C" void kernel_launch(void* const* d_in, const int* in_sizes, int n_in,
                              void* d_out, int out_size, void* d_ws, size_t ws_size,
                              hipStream_t stream) {
  const float* x    = (const float*)d_in[0];
  const float* cosb = (const float*)d_in[1];
  const float* sinb = (const float*)d_in[2];
  const float* wq   = (const float*)d_in[3];
  const float* wk   = (const float*)d_in[4];
  const float* wv   = (const float*)d_in[5];
  const float* wo   = (const float*)d_in[6];
  const float* qnw  = (const float*)d_in[7];
  const float* knw  = (const float*)d_in[8];

  unsigned short* q     = (unsigned short*)d_ws;            // 2048*4096
  unsigned short* k     = q + (size_t)S_LEN * DIM;          // 2048*1024
  unsigned short* vT    = k + (size_t)S_LEN * NKV * HD;     // 1024*2048
  unsigned short* att   = vT + (size_t)NKV * HD * S_LEN;    // 2048*4096
  unsigned short* xb    = att + (size_t)S_LEN * DIM;        // 2048*4096
  unsigned short* wqkvb = xb + (size_t)S_LEN * DIM;         // 6144*4096
  unsigned short* wob   = wqkvb + (size_t)6144 * DIM;       // 4096*4096

  // K0: convert fp32 inputs to bf16
  cvt_all<<<dim3(24576), dim3(256), 0, stream>>>(x, wq, wk, wv, wo, xb, wqkvb,
                                                 wob);
  // K1: QKV projection, N = 6144 -> 48 col tiles (V stored transposed)
  gemm16<1, unsigned short>
      <<<dim3(48, 16), dim3(256), 0, stream>>>(xb, wqkvb, q, k, vT, DIM);
  // K2: RMSNorm + RoPE, one wave per head
  norm_rope<<<dim3(S_LEN, 5), dim3(512), 0, stream>>>(q, k, cosb, sinb,
                                                      qnw, knw);
  // K3: causal MFMA attention, 128 q-rows/block, dbuf + counted prefetch
  attn_mfma<<<dim3(S_LEN / 128, NH), dim3(256), 0, stream>>>(q, k, vT, att);
  // K4: output projection, N = 4096 -> 32 col tiles
  gemm16<0, float>
      <<<dim3(32, 16), dim3(256), 0, stream>>>(att, wob, (float*)d_out,
                                               nullptr, nullptr, DIM);
}

// Round 4
// 526.480 us; speedup vs baseline: 1.1201x; 1.0057x over previous
//
#include <hip/hip_runtime.h>

// ---------------------------------------------------------------------------
// Qwen3VL text-attention block. IO fp32; internal bf16 MFMA + fp32 accum.
//   K0: fp32 -> bf16 streaming convert of x, [wq;wk;wv], wo
//   K1: fused QKV projection GEMM (bf16, global_load_lds; V written TRANSPOSED)
//   K2: per-head RMSNorm + RoPE, ONE WAVE PER HEAD (no LDS, no barriers)
//   K3: causal flash attention, 32 q-rows/wave, double-buffered K/V with
//       counted vmcnt(8) prefetch
//   K4: output projection GEMM, 128x256 tile, 8 waves, grid (16,16) = 256
//       blocks = EXACTLY 1/CU perfect fill; double-buffered counted-vmcnt(6)
//       prefetch (never drains to 0) since there is no co-resident block to
//       hide the staging drain.
// All MFMA LDS tiles use an XOR granule swizzle:
//   slot(row, kg) = row*G + (kg ^ (row & (G-1)))   (granule = 8 bf16 = 16 B)
// ---------------------------------------------------------------------------

#define S_LEN 2048
#define DIM 4096
#define NH 32
#define NKV 8
#define HD 128
#define SCALE 0.08838834764831845f  // 1/sqrt(128)

typedef __attribute__((ext_vector_type(8))) short short8;
typedef __attribute__((ext_vector_type(4))) float f32x4;

__device__ __forceinline__ float bf2f(unsigned short u) {
  union { unsigned i; float f; } c; c.i = ((unsigned)u) << 16; return c.f;
}
__device__ __forceinline__ unsigned short f2bf(float f) {
  union { float f; unsigned u; } c; c.f = f;
  return (unsigned short)((c.u + 0x7fffu + ((c.u >> 16) & 1u)) >> 16);  // RNE
}
__device__ __forceinline__ void cvt8(const float* __restrict__ g,
                                     unsigned short* __restrict__ d) {
  const float4 a = *(const float4*)g;
  const float4 b = *(const float4*)(g + 4);
  short8 p;
  p[0] = (short)f2bf(a.x); p[1] = (short)f2bf(a.y);
  p[2] = (short)f2bf(a.z); p[3] = (short)f2bf(a.w);
  p[4] = (short)f2bf(b.x); p[5] = (short)f2bf(b.y);
  p[6] = (short)f2bf(b.z); p[7] = (short)f2bf(b.w);
  *(short8*)d = p;
}
__device__ __forceinline__ void storeC(float* p, float v) { *p = v; }
__device__ __forceinline__ void storeC(unsigned short* p, float v) { *p = f2bf(v); }

// ---------------------------------------------------------------------------
// K0: fp32 -> bf16 convert. One thread per 8-elem granule.
// ---------------------------------------------------------------------------
#define G_X   1048576u
#define G_WQ  2097152u
#define G_WK   524288u
#define G_WV   524288u
#define G_QKV (G_WQ + G_WK + G_WV)

__global__ __launch_bounds__(256)
void cvt_all(const float* __restrict__ x,  const float* __restrict__ wq,
             const float* __restrict__ wk, const float* __restrict__ wv,
             const float* __restrict__ wo,
             unsigned short* __restrict__ xb,
             unsigned short* __restrict__ wqkvb,
             unsigned short* __restrict__ wob) {
  const size_t g = (size_t)blockIdx.x * 256 + threadIdx.x;
  if (g < G_X) {
    cvt8(x + g * 8, xb + g * 8);
  } else if (g < G_X + G_QKV) {
    const size_t o = g - G_X;
    const float* s = (o < G_WQ) ? wq + o * 8
                   : (o < G_WQ + G_WK) ? wk + (o - G_WQ) * 8
                                       : wv + (o - G_WQ - G_WK) * 8;
    cvt8(s, wqkvb + o * 8);
  } else {
    const size_t o = g - (G_X + G_QKV);
    cvt8(wo + o * 8, wob + o * 8);
  }
}

// ---------------------------------------------------------------------------
// K1: bf16 GEMM, C = A(MxK) @ B^T. 128x128 tile, BK=64, global_load_lds
// staging, 4 waves x (4x4) 16x16x32 MFMA. LDS rows (64 k = 8 granules)
// XOR-swizzled with G=8. 768 blocks = 3 full fill rounds at 3/CU: the
// per-K-step vmcnt(0) drain hides under co-resident blocks (m114 overlap).
// ---------------------------------------------------------------------------
template <int QKV, typename TC>
__global__ __launch_bounds__(256)
void gemm16(const unsigned short* __restrict__ A,
            const unsigned short* __restrict__ B,
            TC* __restrict__ C0,
            unsigned short* __restrict__ Ck,
            unsigned short* __restrict__ Cv, int K) {
  __shared__ unsigned short lsA[128 * 64];
  __shared__ unsigned short lsB[128 * 64];

  const int t    = threadIdx.x;
  const int lane = t & 63;
  const int w    = t >> 6;
  const int m0   = blockIdx.y * 128;
  const int n0   = blockIdx.x * 128;

  f32x4 acc[4][4];
#pragma unroll
  for (int a = 0; a < 4; ++a)
#pragma unroll
    for (int b = 0; b < 4; ++b)
#pragma unroll
      for (int e = 0; e < 4; ++e) acc[a][b][e] = 0.f;

  const int l15  = lane & 15;
  const int qd   = lane >> 4;
  const int wr   = w >> 1, wc = w & 1;
  const int sr8  = lane >> 3;                       // staging row in 8-chunk
  const int skg  = (lane & 7) ^ sr8;                // swizzled staging granule
  const int l7   = l15 & 7;

  const int nkb = K >> 6;
  for (int kb = 0; kb < nkb; ++kb) {
    const int k0 = kb << 6;
#pragma unroll
    for (int c = 0; c < 4; ++c) {
      const int chunk = c * 4 + w;         // wave-uniform
      const int row   = chunk * 8 + sr8;
      const unsigned short* ga = A + (size_t)(m0 + row) * K + k0 + skg * 8;
      const unsigned short* gb = B + (size_t)(n0 + row) * K + k0 + skg * 8;
      __builtin_amdgcn_global_load_lds(
          (const __attribute__((address_space(1))) void*)ga,
          (__attribute__((address_space(3))) void*)(lsA + chunk * 512), 16, 0, 0);
      __builtin_amdgcn_global_load_lds(
          (const __attribute__((address_space(1))) void*)gb,
          (__attribute__((address_space(3))) void*)(lsB + chunk * 512), 16, 0, 0);
    }
    asm volatile("s_waitcnt vmcnt(0)" ::: "memory");
    __syncthreads();

#pragma unroll
    for (int half = 0; half < 2; ++half) {
      const int kg = (half * 4 + qd) ^ l7;  // swizzled read granule
      short8 af[4], bf[4];
#pragma unroll
      for (int mi = 0; mi < 4; ++mi)
        af[mi] = *(const short8*)(lsA + (wr * 64 + mi * 16 + l15) * 64 + kg * 8);
#pragma unroll
      for (int ni = 0; ni < 4; ++ni)
        bf[ni] = *(const short8*)(lsB + (wc * 64 + ni * 16 + l15) * 64 + kg * 8);
#pragma unroll
      for (int mi = 0; mi < 4; ++mi)
#pragma unroll
        for (int ni = 0; ni < 4; ++ni)
          acc[mi][ni] = __builtin_amdgcn_mfma_f32_16x16x32_bf16(
              af[mi], bf[ni], acc[mi][ni], 0, 0, 0);
    }
    __syncthreads();
  }

  // epilogue: C/D layout col=lane&15, row=quad*4+reg
#pragma unroll
  for (int mi = 0; mi < 4; ++mi)
#pragma unroll
    for (int i = 0; i < 4; ++i) {
      const int grow = m0 + wr * 64 + mi * 16 + qd * 4 + i;
#pragma unroll
      for (int ni = 0; ni < 4; ++ni) {
        const int gcol = n0 + wc * 64 + ni * 16 + l15;
        if (QKV) {
          if (n0 < 4096)
            storeC((unsigned short*)C0 + (size_t)grow * 4096 + gcol,
                   acc[mi][ni][i]);
          else if (n0 < 5120)
            Ck[(size_t)grow * 1024 + (gcol - 4096)] = f2bf(acc[mi][ni][i]);
          else  // V transposed: vT[d][token]
            Cv[(size_t)(gcol - 5120) * S_LEN + grow] = f2bf(acc[mi][ni][i]);
        } else {
          storeC(C0 + (size_t)grow * 4096 + gcol, acc[mi][ni][i]);
        }
      }
    }
}

// ---------------------------------------------------------------------------
// K4: bf16 GEMM C = A(2048x4096) @ B^T(4096x4096) -> fp32. 128x256 tile,
// BK=64, 8 waves (2 row-halves x 4 col-groups, each wave 64x64 out).
// Grid (16,16) = 256 blocks = exactly 1/CU. Double-buffered LDS (96 KiB),
// counted prefetch: stage kt+1 (6 loads/wave) before computing kt, then
// s_waitcnt vmcnt(6) + raw s_barrier. +33% FLOP per staged LDS byte vs 128².
// ---------------------------------------------------------------------------
#define WTILE (128 * 64 + 256 * 64)  // shorts per buffer (A 8192 + B 16384)

__global__ __launch_bounds__(512)
void gemm_wide(const unsigned short* __restrict__ A,
               const unsigned short* __restrict__ B,
               float* __restrict__ C0) {
  __shared__ unsigned short ls[2 * WTILE];  // 96 KiB

  const int t    = threadIdx.x;
  const int lane = t & 63;
  const int w    = t >> 6;                 // 0..7
  const int wr   = w >> 2;                 // 0..1 row half
  const int wc   = w & 3;                  // 0..3 col group
  const int m0   = blockIdx.y * 128;
  const int n0   = blockIdx.x * 256;
  const int l15  = lane & 15;
  const int qd   = lane >> 4;
  const int l7   = l15 & 7;
  const int sr8  = lane >> 3;              // staging row within 8-chunk
  const int skg  = (lane & 7) ^ sr8;       // swizzled staging granule

  f32x4 acc[4][4];
#pragma unroll
  for (int a = 0; a < 4; ++a)
#pragma unroll
    for (int b = 0; b < 4; ++b)
#pragma unroll
      for (int e = 0; e < 4; ++e) acc[a][b][e] = 0.f;

#define STAGE_W(KT, BUF)                                                       \
  {                                                                            \
    unsigned short* la = ls + (BUF) * WTILE;                                   \
    unsigned short* lb = la + 8192;                                            \
    const int k0s = (KT) << 6;                                                 \
    _Pragma("unroll")                                                          \
    for (int j = 0; j < 2; ++j) {                                              \
      const int ca  = w * 2 + j;           /* 0..15: A rows ca*8+sr8 */        \
      const unsigned short* ga =                                               \
          A + (size_t)(m0 + ca * 8 + sr8) * DIM + k0s + skg * 8;               \
      __builtin_amdgcn_global_load_lds(                                        \
          (const __attribute__((address_space(1))) void*)ga,                   \
          (__attribute__((address_space(3))) void*)(la + ca * 512), 16, 0, 0); \
    }                                                                          \
    _Pragma("unroll")                                                          \
    for (int j = 0; j < 4; ++j) {                                              \
      const int cb  = w * 4 + j;           /* 0..31: B rows cb*8+sr8 */        \
      const unsigned short* gb =                                               \
          B + (size_t)(n0 + cb * 8 + sr8) * DIM + k0s + skg * 8;               \
      __builtin_amdgcn_global_load_lds(                                        \
          (const __attribute__((address_space(1))) void*)gb,                   \
          (__attribute__((address_space(3))) void*)(lb + cb * 512), 16, 0, 0); \
    }                                                                          \
  }

  // prologue: tile 0 -> buf 0 (latency exposed once)
  STAGE_W(0, 0);

  const int nkb = DIM >> 6;  // 64
  for (int kb = 0; kb < nkb; ++kb) {
    const int cur = kb & 1;
    const int kn  = (kb + 1 < nkb) ? (kb + 1) : kb;  // clamp; dup harmless
    STAGE_W(kn, cur ^ 1);
    // wait only for THIS tile's 6 loads (issued one compute phase ago)
    asm volatile("s_waitcnt vmcnt(6)" ::: "memory");
    __builtin_amdgcn_s_barrier();

    const unsigned short* la = ls + cur * WTILE;
    const unsigned short* lb = la + 8192;

    __builtin_amdgcn_s_setprio(1);
#pragma unroll
    for (int half = 0; half < 2; ++half) {
      const int kg = (half * 4 + qd) ^ l7;  // swizzled read granule
      short8 af[4], bf[4];
#pragma unroll
      for (int mi = 0; mi < 4; ++mi)
        af[mi] = *(const short8*)(la + (wr * 64 + mi * 16 + l15) * 64 + kg * 8);
#pragma unroll
      for (int ni = 0; ni < 4; ++ni)
        bf[ni] = *(const short8*)(lb + (wc * 64 + ni * 16 + l15) * 64 + kg * 8);
#pragma unroll
      for (int mi = 0; mi < 4; ++mi)
#pragma unroll
        for (int ni = 0; ni < 4; ++ni)
          acc[mi][ni] = __builtin_amdgcn_mfma_f32_16x16x32_bf16(
              af[mi], bf[ni], acc[mi][ni], 0, 0, 0);
    }
    __builtin_amdgcn_s_setprio(0);
    // all reads of `cur` done before next iter re-stages into it
    __builtin_amdgcn_s_barrier();
  }

  // epilogue: C/D layout col=lane&15, row=quad*4+reg
#pragma unroll
  for (int mi = 0; mi < 4; ++mi)
#pragma unroll
    for (int i = 0; i < 4; ++i) {
      const int grow = m0 + wr * 64 + mi * 16 + qd * 4 + i;
#pragma unroll
      for (int ni = 0; ni < 4; ++ni) {
        const int gcol = n0 + wc * 64 + ni * 16 + l15;
        C0[(size_t)grow * 4096 + gcol] = acc[mi][ni][i];
      }
    }
#undef STAGE_W
}

// ---------------------------------------------------------------------------
// K2: RMSNorm + RoPE, ONE WAVE PER HEAD. Lane l owns dims {l, l+64} -- the
// rotate-half pair is lane-local; RMS reduce is a 64-lane shuffle butterfly.
// No LDS, no barriers. Grid (S, 5) x 512 thr = 8 heads per block.
// ---------------------------------------------------------------------------
__global__ __launch_bounds__(512)
void norm_rope(unsigned short* __restrict__ qb, unsigned short* __restrict__ kb,
               const float* __restrict__ cosb, const float* __restrict__ sinb,
               const float* __restrict__ qw, const float* __restrict__ kw) {
  const int s    = blockIdx.x;
  const int w    = threadIdx.x >> 6;
  const int l    = threadIdx.x & 63;
  const int hh   = blockIdx.y * 8 + w;            // 0..39

  unsigned short* p; const float* wt;
  if (hh < NH) { p = qb + (size_t)s * (NH * HD) + hh * HD; wt = qw; }
  else         { p = kb + (size_t)s * (NKV * HD) + (hh - NH) * HD; wt = kw; }

  const float v0 = bf2f(p[l]);
  const float v1 = bf2f(p[l + 64]);
  float ss = v0 * v0 + v1 * v1;
#pragma unroll
  for (int off = 32; off; off >>= 1) ss += __shfl_xor(ss, off);
  const float r = rsqrtf(ss * (1.f / 128.f) + 1e-6f);

  const float xn0 = v0 * r * wt[l];
  const float xn1 = v1 * r * wt[l + 64];
  const float c0 = cosb[s * HD + l],      s0 = sinb[s * HD + l];
  const float c1 = cosb[s * HD + l + 64], s1 = sinb[s * HD + l + 64];
  float o0 = xn0 * c0 - xn1 * s0;
  float o1 = xn1 * c1 + xn0 * s1;
  if (hh < NH) { o0 *= SCALE; o1 *= SCALE; }  // fold softmax scale into q
  p[l]      = f2bf(o0);
  p[l + 64] = f2bf(o1);
}

// ---------------------------------------------------------------------------
// K3: causal flash attention, MFMA. 4 waves/block, 128 q-rows/block,
// 32 q-rows (2 q-frags) per wave. Double-buffered K/V, counted vmcnt(8)
// prefetch. ks: [key][dgran^key&15]; vt: [d][kgran^d&7]. Fixed-max softmax,
// deferred l-reduction. LDS 73 KB -> 2 blocks/CU.
// ---------------------------------------------------------------------------
#define PSTR 72  // P row stride (shorts)

#define STAGE_KV(KT, BUF)                                                      \
  {                                                                            \
    unsigned short* ksb = ks + (BUF) * 8192;                                   \
    unsigned short* vtb = vt + (BUF) * 8192;                                   \
    _Pragma("unroll")                                                          \
    for (int c = 0; c < 4; ++c) {                                              \
      const int chunk = w * 4 + c;                                             \
      const int key = chunk * 4 + kr16;                                        \
      const int dg  = (lane & 15) ^ (key & 15);                                \
      const unsigned short* gk = kB + (size_t)((KT) * 64 + key) * (NKV * HD) + \
                                 kvh * HD + dg * 8;                            \
      __builtin_amdgcn_global_load_lds(                                        \
          (const __attribute__((address_space(1))) void*)gk,                   \
          (__attribute__((address_space(3))) void*)(ksb + chunk * 512),        \
          16, 0, 0);                                                           \
      const int dv = chunk * 8 + vr8;                                          \
      const unsigned short* gv = vT + (size_t)(kvh * HD + dv) * S_LEN +        \
                                 (KT) * 64 + vkg * 8;                          \
      __builtin_amdgcn_global_load_lds(                                        \
          (const __attribute__((address_space(1))) void*)gv,                   \
          (__attribute__((address_space(3))) void*)(vtb + chunk * 512),        \
          16, 0, 0);                                                           \
    }                                                                          \
  }

__global__ __launch_bounds__(256)
void attn_mfma(const unsigned short* __restrict__ qB,
               const unsigned short* __restrict__ kB,
               const unsigned short* __restrict__ vT,
               unsigned short* __restrict__ oB) {
  __shared__ unsigned short ks[2 * 64 * 128];  // dbuf [key][16 gran, swz]
  __shared__ unsigned short vt[2 * 64 * 128];  // dbuf [d][8 gran, swz]
  __shared__ unsigned short Ps[4 * 16 * PSTR]; // per-wave 16-row P buffer

  const int t    = threadIdx.x;
  const int lane = t & 63;
  const int w    = t >> 6;
  const int h    = blockIdx.y;
  const int qt   = (h & 16) ? (15 - blockIdx.x) : blockIdx.x;  // pair-balanced
  const int q0   = qt * 128;
  const int kvh  = h >> 2;
  const int l15  = lane & 15;
  const int qd   = lane >> 4;
  const int l7   = l15 & 7;

  // staging index helpers
  const int kr16 = lane >> 4;                 // K staging: row within 4-chunk
  const int vr8  = lane >> 3;                 // V staging: row within 8-chunk
  const int vkg  = (lane & 7) ^ (vr8 & 7);    // V staging swizzled granule

  // preload Q A-fragments for 2 q-frags (q pre-scaled by 1/sqrt(d))
  short8 qf[2][4];
#pragma unroll
  for (int f = 0; f < 2; ++f) {
    const unsigned short* qp =
        qB + (size_t)(q0 + w * 32 + f * 16 + l15) * (NH * HD) + h * HD + qd * 8;
#pragma unroll
    for (int s = 0; s < 4; ++s) qf[f][s] = *(const short8*)(qp + s * 32);
  }

  f32x4 O[2][8];
#pragma unroll
  for (int f = 0; f < 2; ++f)
#pragma unroll
    for (int nt = 0; nt < 8; ++nt)
#pragma unroll
      for (int e = 0; e < 4; ++e) O[f][nt][e] = 0.f;
  float l_i[2][4] = {{0.f, 0.f, 0.f, 0.f}, {0.f, 0.f, 0.f, 0.f}};

  unsigned short* Pw = Ps + w * (16 * PSTR);

  const int nkt = 2 * qt + 2;  // tiles of 64 keys covering q0..q0+127

  // prologue: stage tile 0 into buffer 0
  STAGE_KV(0, 0);

  for (int kt = 0; kt < nkt; ++kt) {
    const int cur = kt & 1;
    const int kn  = (kt + 1 < nkt) ? (kt + 1) : kt;  // clamp (dup harmless)
    STAGE_KV(kn, cur ^ 1);
    // wait only for THIS tile's 8 loads (issued one compute-phase ago)
    asm volatile("s_waitcnt vmcnt(8)" ::: "memory");
    __builtin_amdgcn_s_barrier();

    const unsigned short* ksb = ks + cur * 8192;
    const unsigned short* vtb = vt + cur * 8192;

    const int dk = kt - 2 * qt;                 // >=0 on diagonal tiles
    const bool active = (dk <= 0) || (w >= 2);  // wave-uniform
    if (active) {
      // ---- QK^T: reuse each kf across both q-frags
      f32x4 S[2][4];
      __builtin_amdgcn_s_setprio(1);
#pragma unroll
      for (int ct = 0; ct < 4; ++ct) {
#pragma unroll
        for (int e = 0; e < 4; ++e) { S[0][ct][e] = 0.f; S[1][ct][e] = 0.f; }
#pragma unroll
        for (int s = 0; s < 4; ++s) {
          const int kg = (s * 4 + qd) ^ l15;  // G=16 swizzle
          const short8 kf =
              *(const short8*)(ksb + (ct * 16 + l15) * 128 + kg * 8);
          S[0][ct] = __builtin_amdgcn_mfma_f32_16x16x32_bf16(qf[0][s], kf,
                                                             S[0][ct], 0, 0, 0);
          S[1][ct] = __builtin_amdgcn_mfma_f32_16x16x32_bf16(qf[1][s], kf,
                                                             S[1][ct], 0, 0, 0);
        }
      }
      __builtin_amdgcn_s_setprio(0);

      // ---- causal mask (diagonal tiles)
      if (dk >= 0) {
#pragma unroll
        for (int f = 0; f < 2; ++f)
#pragma unroll
          for (int ct = 0; ct < 4; ++ct)
#pragma unroll
            for (int i = 0; i < 4; ++i) {
              const int krel = dk * 64 + ct * 16 + l15;
              const int rrel = w * 32 + f * 16 + qd * 4 + i;
              if (krel > rrel) S[f][ct][i] = -1e30f;
            }
      }

      // ---- P = exp(S) per q-frag: write 16-row P, read A-frags back
      short8 pf[2][2];
#pragma unroll
      for (int f = 0; f < 2; ++f) {
#pragma unroll
        for (int ct = 0; ct < 4; ++ct)
#pragma unroll
          for (int i = 0; i < 4; ++i) {
            const float e = __expf(S[f][ct][i]);
            l_i[f][i] += e;
            Pw[(qd * 4 + i) * PSTR + ct * 16 + l15] = f2bf(e);
          }
        // per-wave DS ops are in-order: these reads complete before the
        // next f's writes to the same rows land
        pf[f][0] = *(const short8*)(Pw + l15 * PSTR + qd * 8);
        pf[f][1] = *(const short8*)(Pw + l15 * PSTR + 32 + qd * 8);
      }

      // ---- PV: O[f] += P[f](16x64) * V(64x128); vf reused across f
      {
        const int kg0 = qd ^ l7;        // half 0, G=8 swizzle (d&7 = l7)
        const int kg1 = (4 + qd) ^ l7;  // half 1
        __builtin_amdgcn_s_setprio(1);
#pragma unroll
        for (int nt = 0; nt < 8; ++nt) {
          const short8 vf0 =
              *(const short8*)(vtb + (nt * 16 + l15) * 64 + kg0 * 8);
          const short8 vf1 =
              *(const short8*)(vtb + (nt * 16 + l15) * 64 + kg1 * 8);
          O[0][nt] = __builtin_amdgcn_mfma_f32_16x16x32_bf16(pf[0][0], vf0,
                                                             O[0][nt], 0, 0, 0);
          O[1][nt] = __builtin_amdgcn_mfma_f32_16x16x32_bf16(pf[1][0], vf0,
                                                             O[1][nt], 0, 0, 0);
          O[0][nt] = __builtin_amdgcn_mfma_f32_16x16x32_bf16(pf[0][1], vf1,
                                                             O[0][nt], 0, 0, 0);
          O[1][nt] = __builtin_amdgcn_mfma_f32_16x16x32_bf16(pf[1][1], vf1,
                                                             O[1][nt], 0, 0, 0);
        }
        __builtin_amdgcn_s_setprio(0);
      }
    }
    // compute on `cur` done before next iter's prefetch overwrites it
    __builtin_amdgcn_s_barrier();
    __builtin_amdgcn_sched_barrier(0);
  }

  // ---- deferred l reduction (16-lane butterfly), then scaled store
  float linv[2][4];
#pragma unroll
  for (int f = 0; f < 2; ++f)
#pragma unroll
    for (int i = 0; i < 4; ++i) {
      float s = l_i[f][i];
#pragma unroll
      for (int off = 1; off < 16; off <<= 1) s += __shfl_xor(s, off);
      linv[f][i] = 1.f / s;
    }
#pragma unroll
  for (int f = 0; f < 2; ++f)
#pragma unroll
    for (int nt = 0; nt < 8; ++nt)
#pragma unroll
      for (int i = 0; i < 4; ++i) {
        const size_t row = (size_t)(q0 + w * 32 + f * 16 + qd * 4 + i);
        oB[row * (NH * HD) + h * HD + nt * 16 + l15] =
            f2bf(O[f][nt][i] * linv[f][i]);
      }
}

// ---------------------------------------------------------------------------
extern "C" void kernel_launch(void* const* d_in, const int* in_sizes, int n_in,
                              void* d_out, int out_size, void* d_ws, size_t ws_size,
                              hipStream_t stream) {
  const float* x    = (const float*)d_in[0];
  const float* cosb = (const float*)d_in[1];
  const float* sinb = (const float*)d_in[2];
  const float* wq   = (const float*)d_in[3];
  const float* wk   = (const float*)d_in[4];
  const float* wv   = (const float*)d_in[5];
  const float* wo   = (const float*)d_in[6];
  const float* qnw  = (const float*)d_in[7];
  const float* knw  = (const float*)d_in[8];

  unsigned short* q     = (unsigned short*)d_ws;            // 2048*4096
  unsigned short* k     = q + (size_t)S_LEN * DIM;          // 2048*1024
  unsigned short* vT    = k + (size_t)S_LEN * NKV * HD;     // 1024*2048
  unsigned short* att   = vT + (size_t)NKV * HD * S_LEN;    // 2048*4096
  unsigned short* xb    = att + (size_t)S_LEN * DIM;        // 2048*4096
  unsigned short* wqkvb = xb + (size_t)S_LEN * DIM;         // 6144*4096
  unsigned short* wob   = wqkvb + (size_t)6144 * DIM;       // 4096*4096

  // K0: convert fp32 inputs to bf16
  cvt_all<<<dim3(24576), dim3(256), 0, stream>>>(x, wq, wk, wv, wo, xb, wqkvb,
                                                 wob);
  // K1: QKV projection, N = 6144 -> 48 col tiles (V stored transposed)
  gemm16<1, unsigned short>
      <<<dim3(48, 16), dim3(256), 0, stream>>>(xb, wqkvb, q, k, vT, DIM);
  // K2: RMSNorm + RoPE, one wave per head
  norm_rope<<<dim3(S_LEN, 5), dim3(512), 0, stream>>>(q, k, cosb, sinb,
                                                      qnw, knw);
  // K3: causal MFMA attention, 128 q-rows/block, dbuf + counted prefetch
  attn_mfma<<<dim3(S_LEN / 128, NH), dim3(256), 0, stream>>>(q, k, vT, att);
  // K4: output projection, 128x256 tile -> grid (16,16) = 256 blocks = 1/CU
  gemm_wide<<<dim3(16, 16), dim3(512), 0, stream>>>(att, wob, (float*)d_out);
}